// Round 2
// baseline (1197.141 us; speedup 1.0000x reference)
//
#include <hip/hip_runtime.h>
#include <hip/hip_bf16.h>
#include <hip/hip_fp16.h>

#define T_STEPS 512
#define BATCH   64
#define DIM     512            // INPUT_DIM == RNN_DIM
#define ROWS    16             // batch rows per workgroup (4 WGs)

typedef _Float16 half2_t __attribute__((ext_vector_type(2)));
typedef _Float16 half8_t __attribute__((ext_vector_type(8)));
typedef short    bf16x8 __attribute__((ext_vector_type(8)));
typedef float    f32x4  __attribute__((ext_vector_type(4)));

static __device__ __forceinline__ unsigned short f2bf(float f) {
    union { float f; unsigned u; } v; v.f = f;
    unsigned r = v.u + 0x7fffu + ((v.u >> 16) & 1u);   // RNE
    return (unsigned short)(r >> 16);
}

static __device__ __forceinline__ float fast_tanh(float x) {
    float e = __expf(2.0f * x);
    return 1.0f - 2.0f * __builtin_amdgcn_rcpf(e + 1.0f);
}

// ------------- K1: transpose 512x512 fp32 region -> bf16 (for Wx^T, gemm B-operand) -------------
__global__ __launch_bounds__(256) void tr_cvt_kernel(const float* __restrict__ src,
                                                     unsigned short* __restrict__ dst) {
    __shared__ float tile[32][33];
    const int bx = blockIdx.x * 32;
    const int by = blockIdx.y * 32;
    const int tx = threadIdx.x;       // 32
    const int ty = threadIdx.y;       // 8
    #pragma unroll
    for (int i = ty; i < 32; i += 8)
        tile[i][tx] = src[(size_t)(by + i) * DIM + (bx + tx)];
    __syncthreads();
    #pragma unroll
    for (int i = ty; i < 32; i += 8)
        dst[(size_t)(bx + i) * DIM + (by + tx)] = f2bf(tile[tx][i]);
}

// ------------- K1c: transpose Wh (rows 512..1023 of W) -> f16 WhT[col][k] -------------
__global__ __launch_bounds__(256) void tr_cvt_f16_kernel(const float* __restrict__ src,  // W + 512*512
                                                         _Float16* __restrict__ dst) {  // [512 col][512 k]
    __shared__ float tile[32][33];
    const int bx = blockIdx.x * 32;
    const int by = blockIdx.y * 32;
    const int tx = threadIdx.x;
    const int ty = threadIdx.y;
    #pragma unroll
    for (int i = ty; i < 32; i += 8)
        tile[i][tx] = src[(size_t)(by + i) * DIM + (bx + tx)];
    __syncthreads();
    #pragma unroll
    for (int i = ty; i < 32; i += 8)
        dst[(size_t)(bx + i) * DIM + (by + tx)] = (_Float16)tile[tx][i];
}

// ---------------- K2: Z = X @ Wx + bias  (bf16 MFMA), output in K3 per-thread frag order --------
// Zws[t][b][w][l][i]: i = ct*4+rg for value at (batch row = b*16 + (l>>4)*4+rg,
//                                              col = w*64 + ct*16 + (l&15))
__global__ __launch_bounds__(256) void gemm_z_kernel(const float* __restrict__ X,            // [32768][512] f32
                                                     const unsigned short* __restrict__ WxT, // [512 n][512 k] bf16
                                                     const float* __restrict__ bias,         // [512]
                                                     _Float16* __restrict__ Zo) {            // [512][4][8][64][16] f16
    const int bm   = blockIdx.y;
    const int bn   = blockIdx.x;
    const int wave = threadIdx.x >> 6;
    const int lane = threadIdx.x & 63;
    const int mBase = bm * 128 + (wave >> 1) * 64;
    const int nBase = bn * 128 + (wave & 1) * 64;
    const int l15 = lane & 15;
    const int q   = lane >> 4;
    f32x4 acc[4][4] = {};
    for (int kt = 0; kt < 512; kt += 32) {
        const int kk = kt + q * 8;
        bf16x8 a[4], b[4];
        #pragma unroll
        for (int i = 0; i < 4; ++i) {
            const float* ap = X + (size_t)(mBase + i * 16 + l15) * DIM + kk;
            float4 f0 = *(const float4*)(ap);
            float4 f1 = *(const float4*)(ap + 4);
            bf16x8 av;
            av[0] = (short)f2bf(f0.x); av[1] = (short)f2bf(f0.y);
            av[2] = (short)f2bf(f0.z); av[3] = (short)f2bf(f0.w);
            av[4] = (short)f2bf(f1.x); av[5] = (short)f2bf(f1.y);
            av[6] = (short)f2bf(f1.z); av[7] = (short)f2bf(f1.w);
            a[i] = av;
        }
        #pragma unroll
        for (int i = 0; i < 4; ++i)
            b[i] = *(const bf16x8*)(WxT + (size_t)(nBase + i * 16 + l15) * DIM + kk);
        #pragma unroll
        for (int mi = 0; mi < 4; ++mi)
            #pragma unroll
            for (int ni = 0; ni < 4; ++ni)
                acc[mi][ni] = __builtin_amdgcn_mfma_f32_16x16x32_bf16(a[mi], b[ni], acc[mi][ni], 0, 0, 0);
    }
    #pragma unroll
    for (int ni = 0; ni < 4; ++ni) {
        const int col = nBase + ni * 16 + l15;
        const float bv = bias[col];
        const int w_ = col >> 6, ct_ = (col >> 4) & 3, l15_ = col & 15;
        #pragma unroll
        for (int mi = 0; mi < 4; ++mi) {
            #pragma unroll
            for (int rg = 0; rg < 4; ++rg) {
                const int row = mBase + mi * 16 + q * 4 + rg;
                const int t_ = row >> 6, brow = row & 63;
                const int b_ = brow >> 4, r4 = brow & 15;
                const int l_ = (r4 >> 2) * 16 + l15_;
                const int i_ = ct_ * 4 + (r4 & 3);
                Zo[(size_t)t_ * 32768 + (size_t)((b_ * 8 + w_) * 64 + l_) * 16 + i_] =
                    (_Float16)(acc[mi][ni][rg] + bv);
            }
        }
    }
}

// ---------------- K3: MFMA recurrence, 4 WGs x 512 thr; 16 batch rows per WG ----------------
// Wave w owns cols [w*64, w*64+64): 4 col-tiles of 16. mfma_f32_16x16x32_f16:
//   A-frag (h):  lane holds h[row=l&15][k=kt*32+(l>>4)*8+e]
//   B-frag (W):  lane holds WhT[col=ct*16+l15+wbase][same k]  -> C[row=(l>>4)*4+rg][col=l15]
// W: kt 0..11 resident in 192 regs (AGPR-safe: MFMA reads AGPRs natively), kt 12..15 in LDS
// (128 KB, frag-linear). h in 16 KB LDS buffer, frag-SLOT-permuted so the 16 scatter
// ds_write_b16/thread hit all 32 banks (2-way only) while reads stay linear b128.
// slot(lane') = (lane'&3)*16 + (lane'>>2); elem index = kt*512 + slot*8 + e.
__global__ __launch_bounds__(512, 2) void rnn_mfma_kernel(const _Float16* __restrict__ Zw,   // [512][4][8][64][16]
                                                          const _Float16* __restrict__ WhT, // [512 col][512 k]
                                                          const float* __restrict__ h0,     // [512]
                                                          float* __restrict__ out) {        // [T][B][512]
    __shared__ _Float16 WlA[65536];   // 128 KB: (w*16 + ct*4 + ktl)*512 + l*8
    __shared__ _Float16 Ah[8192];     //  16 KB: kt*512 + slot*8
    const int tid = threadIdx.x;
    const int w = tid >> 6, l = tid & 63;
    const int l15 = l & 15, q = l >> 4;
    const int b = blockIdx.x;               // batch rows b*16 .. b*16+15
    const int wbase = w * 64;

    // ---- stage register B-fragments (kt 0..11): 192 regs
    half8_t bw[12][4];
    #pragma unroll
    for (int kt = 0; kt < 12; ++kt)
        #pragma unroll
        for (int ct = 0; ct < 4; ++ct)
            bw[kt][ct] = *(const half8_t*)(WhT + (size_t)(wbase + ct * 16 + l15) * DIM + kt * 32 + q * 8);
    #pragma unroll
    for (int kt = 0; kt < 12; ++kt)
        #pragma unroll
        for (int ct = 0; ct < 4; ++ct)
            asm volatile("" : "+v"(bw[kt][ct]));
    // ---- stage LDS B-fragments (kt 12..15), frag-linear: read & write conflict-free
    #pragma unroll
    for (int ktl = 0; ktl < 4; ++ktl)
        #pragma unroll
        for (int ct = 0; ct < 4; ++ct) {
            half8_t v = *(const half8_t*)(WhT + (size_t)(wbase + ct * 16 + l15) * DIM + (12 + ktl) * 32 + q * 8);
            *(half8_t*)(WlA + (size_t)((w * 16 + ct * 4 + ktl) * 512 + l * 8)) = v;
        }

    // ---- h0: out[0] plane (exact f32 passthrough) + Ah init (f16)
    const int hi = l15 >> 3, l7 = l15 & 7;
    const int abase = w * 1024 + hi * 32 + q * 8 + l7;     // + (ct>>1)*512 + (ct&1)*64 + rg*128
    float* p0 = out + (size_t)(b * 16 + q * 4) * DIM + wbase + l15;
    float h0c[4];
    #pragma unroll
    for (int ct = 0; ct < 4; ++ct) h0c[ct] = h0[wbase + ct * 16 + l15];
    #pragma unroll
    for (int ct = 0; ct < 4; ++ct)
        #pragma unroll
        for (int rg = 0; rg < 4; ++rg) {
            p0[rg * DIM + ct * 16] = h0c[ct];
            Ah[abase + (ct >> 1) * 512 + (ct & 1) * 64 + rg * 128] = (_Float16)h0c[ct];
        }
    __syncthreads();

    const int aslot = (l & 3) * 128 + (l >> 2) * 8;        // read slot base (elems)
    const _Float16* pz = Zw + ((size_t)(b * 8 + w) * 64 + l) * 16;
    half8_t z0 = *(const half8_t*)(pz);
    half8_t z1 = *(const half8_t*)(pz + 8);
    float* pout = out + (size_t)(BATCH + b * 16 + q * 4) * DIM + wbase + l15;   // t=1 plane

    for (int t = 0; t < T_STEPS - 1; ++t) {
        // acc init = z_t (f16 -> f32); frees z regs immediately
        f32x4 acc[4];
        #pragma unroll
        for (int ct = 0; ct < 4; ++ct)
            #pragma unroll
            for (int rg = 0; rg < 4; ++rg) {
                const int i = ct * 4 + rg;
                acc[ct][rg] = (float)(i < 8 ? z0[i] : z1[i - 8]);
            }
        // prefetch z_{t+1} (in flight across the MFMA phase)
        half8_t zn0 = *(const half8_t*)(pz + (size_t)(t + 1) * 32768);
        half8_t zn1 = *(const half8_t*)(pz + (size_t)(t + 1) * 32768 + 8);

        // ---- MFMA phase: 16 k-tiles x 4 col-tiles = 64 MFMA
        #pragma unroll
        for (int kt = 0; kt < 12; ++kt) {
            half8_t af = *(const half8_t*)(Ah + kt * 512 + aslot);
            #pragma unroll
            for (int ct = 0; ct < 4; ++ct)
                acc[ct] = __builtin_amdgcn_mfma_f32_16x16x32_f16(af, bw[kt][ct], acc[ct], 0, 0, 0);
        }
        #pragma unroll
        for (int ktl = 0; ktl < 4; ++ktl) {
            half8_t af = *(const half8_t*)(Ah + (12 + ktl) * 512 + aslot);
            #pragma unroll
            for (int ct = 0; ct < 4; ++ct) {
                half8_t wf = *(const half8_t*)(WlA + (size_t)((w * 16 + ct * 4 + ktl) * 512 + l * 8));
                acc[ct] = __builtin_amdgcn_mfma_f32_16x16x32_f16(af, wf, acc[ct], 0, 0, 0);
            }
        }
        // all waves' Ah reads done before anyone overwrites (single h buffer)
        asm volatile("s_waitcnt lgkmcnt(0)\n\ts_barrier" ::: "memory");
        // ---- epilogue: tanh, f32 out store (vmcnt never drained), f16 scatter to Ah
        #pragma unroll
        for (int ct = 0; ct < 4; ++ct)
            #pragma unroll
            for (int rg = 0; rg < 4; ++rg) {
                const float hv = fast_tanh(acc[ct][rg]);
                pout[rg * DIM + ct * 16] = hv;
                Ah[abase + (ct >> 1) * 512 + (ct & 1) * 64 + rg * 128] = (_Float16)hv;
            }
        asm volatile("s_waitcnt lgkmcnt(0)\n\ts_barrier" ::: "memory");
        pout += BATCH * DIM;
        z0 = zn0; z1 = zn1;
    }
}

extern "C" void kernel_launch(void* const* d_in, const int* in_sizes, int n_in,
                              void* d_out, int out_size, void* d_ws, size_t ws_size,
                              hipStream_t stream) {
    const float* X    = (const float*)d_in[0];   // [512][64][512]
    const float* W    = (const float*)d_in[1];   // [1024][512]
    const float* bias = (const float*)d_in[2];   // [512]
    const float* h0   = (const float*)d_in[3];   // [512]
    float* out = (float*)d_out;

    char* ws = (char*)d_ws;
    unsigned short* WxT = (unsigned short*)(ws);                 //    524,288 B
    _Float16*       WhT = (_Float16*)(ws + 524288);              //    524,288 B  [col][k] f16
    _Float16*       Zws = (_Float16*)(ws + 1048576);             // 33,554,432 B  frag-ordered Z
                                                                  // total 34,603,008 B

    dim3 tb(32, 8);
    tr_cvt_kernel<<<dim3(16, 16), tb, 0, stream>>>(W, WxT);                    // Wx^T bf16
    tr_cvt_f16_kernel<<<dim3(16, 16), tb, 0, stream>>>(W + 512 * 512, WhT);    // Wh^T f16
    gemm_z_kernel<<<dim3(4, 256), 256, 0, stream>>>(X, WxT, bias, Zws);
    rnn_mfma_kernel<<<4, 512, 0, stream>>>(Zws, WhT, h0, out);
}